// Round 1
// baseline (114.276 us; speedup 1.0000x reference)
//
#include <hip/hip_runtime.h>
#include <hip/hip_bf16.h>
#include <math.h>

typedef unsigned short u16;
typedef __bf16 bf16x8 __attribute__((ext_vector_type(8)));
typedef float f32x4 __attribute__((ext_vector_type(4)));
typedef unsigned short u16x4 __attribute__((ext_vector_type(4)));

#define NROW 4096
#define KDIM 1024
#define MDIM 8192
#define TILE 128
#define BK 64
#define NCT (NROW / TILE)   // 32 column tiles

__device__ __forceinline__ u16 f2bf(float x) {
    unsigned int u = __float_as_uint(x);
    unsigned int r = (u + 0x7fffu + ((u >> 16) & 1u)) >> 16;
    return (u16)r;
}

__device__ __forceinline__ void gload16(const u16* g, u16* l) {
    __builtin_amdgcn_global_load_lds(
        (const __attribute__((address_space(1))) void*)g,
        (__attribute__((address_space(3))) void*)l,
        16, 0, 0);
}

// ---------------- Kernel A: row-normalize q -> bf16 ----------------
__global__ void k_normalize(const float* __restrict__ q, u16* __restrict__ qn) {
    const int r = blockIdx.x;
    const int t = threadIdx.x;          // 256 threads
    const int lane = t & 63, wid = t >> 6;
    const float4* qr = (const float4*)(q + (size_t)r * KDIM);
    float4 v = qr[t];                   // 256*4 = 1024
    float ss = v.x * v.x + v.y * v.y + v.z * v.z + v.w * v.w;
    #pragma unroll
    for (int d = 1; d < 64; d <<= 1) ss += __shfl_xor(ss, d);
    __shared__ float red[4];
    if (lane == 0) red[wid] = ss;
    __syncthreads();
    float tot = red[0] + red[1] + red[2] + red[3];
    float nrm = sqrtf(tot);
    float inv = 1.0f / fmaxf(nrm, 1e-8f);
    u16x4 o;
    o[0] = f2bf(v.x * inv); o[1] = f2bf(v.y * inv);
    o[2] = f2bf(v.z * inv); o[3] = f2bf(v.w * inv);
    *(u16x4*)(qn + (size_t)r * KDIM + t * 4) = o;
}

// ---------------- Kernel B: per-row memory stats ----------------
// out[r] = {S2 = sum exp(ml), dot = sum mt*ml, smt = sum mt, 0}
__global__ void k_memstats(const float* __restrict__ ml, const float* __restrict__ mt,
                           float4* __restrict__ out) {
    const int r = blockIdx.x;
    const int t = threadIdx.x;          // 256
    const int lane = t & 63, wid = t >> 6;
    const float4* pl = (const float4*)(ml + (size_t)r * MDIM);
    const float4* pt = (const float4*)(mt + (size_t)r * MDIM);
    float S2 = 0.f, dot = 0.f, smt = 0.f;
    #pragma unroll
    for (int it = 0; it < MDIM / 4 / 256; ++it) {
        int idx = it * 256 + t;
        float4 l = pl[idx];
        float4 m = pt[idx];
        S2 += __expf(l.x) + __expf(l.y) + __expf(l.z) + __expf(l.w);
        dot += m.x * l.x + m.y * l.y + m.z * l.z + m.w * l.w;
        smt += m.x + m.y + m.z + m.w;
    }
    #pragma unroll
    for (int d = 1; d < 64; d <<= 1) {
        S2  += __shfl_xor(S2, d);
        dot += __shfl_xor(dot, d);
        smt += __shfl_xor(smt, d);
    }
    __shared__ float red[4][3];
    if (lane == 0) { red[wid][0] = S2; red[wid][1] = dot; red[wid][2] = smt; }
    __syncthreads();
    if (t == 0) {
        out[r] = make_float4(red[0][0] + red[1][0] + red[2][0] + red[3][0],
                             red[0][1] + red[1][1] + red[2][1] + red[3][1],
                             red[0][2] + red[1][2] + red[2][2] + red[3][2], 0.f);
    }
}

// ---------------- Kernel C: sims GEMM + fused row stats ----------------
// partials[ct*NROW + i] = {rowmax m (over this 128-col tile, incl diag),
//                          sum exp(c - m) excl diag, sum t*c, count t}
__global__ void k_gemm_stats(const u16* __restrict__ qn, const int* __restrict__ labels,
                             float4* __restrict__ partials) {
    __shared__ u16 ldsA[TILE * BK];
    __shared__ u16 ldsB[TILE * BK];
    __shared__ int labR[TILE], labC[TILE];

    const int ct = blockIdx.x, bi = blockIdx.y;
    const int t = threadIdx.x;
    const int w = t >> 6, lane = t & 63;
    const int rowbase = bi * TILE, colbase = ct * TILE;

    if (t < 128) labR[t] = labels[rowbase + t];
    else labC[t - 128] = labels[colbase + (t - 128)];

    const int wr = (w >> 1) * 64, wc = (w & 1) * 64;   // wave's 64x64 quadrant
    const int cl = lane & 15, cg = lane >> 4;

    // staging geometry: chunk c = w*4+it covers 1024 B of LDS; lane writes c*1024 + lane*16
    const int sr = lane >> 3;   // row within chunk (8 rows per 1 KB chunk, 128 B/row)
    const int skb = lane & 7;   // 16-byte slot within row

    f32x4 acc[4][4];
    #pragma unroll
    for (int i = 0; i < 4; ++i)
        #pragma unroll
        for (int j = 0; j < 4; ++j)
            acc[i][j] = {0.f, 0.f, 0.f, 0.f};

    for (int ks = 0; ks < KDIM / BK; ++ks) {
        const int k0 = ks * BK;
        #pragma unroll
        for (int it = 0; it < 4; ++it) {
            int c = w * 4 + it;
            int rr = c * 8 + sr;
            const u16* ga = qn + (size_t)(rowbase + rr) * KDIM + k0 + skb * 8;
            gload16(ga, ldsA + c * 512);
            const u16* gb = qn + (size_t)(colbase + rr) * KDIM + k0 + skb * 8;
            gload16(gb, ldsB + c * 512);
        }
        asm volatile("s_waitcnt vmcnt(0)" ::: "memory");
        __syncthreads();
        #pragma unroll
        for (int k2 = 0; k2 < 2; ++k2) {
            bf16x8 a[4], b[4];
            #pragma unroll
            for (int f = 0; f < 4; ++f) {
                a[f] = *(const bf16x8*)&ldsA[(wr + f * 16 + cl) * BK + k2 * 32 + cg * 8];
                b[f] = *(const bf16x8*)&ldsB[(wc + f * 16 + cl) * BK + k2 * 32 + cg * 8];
            }
            #pragma unroll
            for (int fm = 0; fm < 4; ++fm)
                #pragma unroll
                for (int fn = 0; fn < 4; ++fn)
                    acc[fm][fn] = __builtin_amdgcn_mfma_f32_16x16x32_bf16(
                        a[fm], b[fn], acc[fm][fn], 0, 0, 0);
        }
        __syncthreads();
    }

    // Epilogue: per-row (within this 128-col tile) stats.
    // C-layout (m89): col = lane&15, row = (lane>>4)*4 + reg.
    const float invT = (float)(1.0 / 0.07);
    #pragma unroll
    for (int fm = 0; fm < 4; ++fm) {
        #pragma unroll
        for (int reg = 0; reg < 4; ++reg) {
            const int lr = wr + fm * 16 + cg * 4 + reg;   // local row
            const int gi = rowbase + lr;                  // global row
            const int li = labR[lr];
            float c0 = acc[fm][0][reg] * invT;
            float c1 = acc[fm][1][reg] * invT;
            float c2 = acc[fm][2][reg] * invT;
            float c3 = acc[fm][3][reg] * invT;
            float m = fmaxf(fmaxf(c0, c1), fmaxf(c2, c3));
            #pragma unroll
            for (int d = 1; d < 16; d <<= 1) m = fmaxf(m, __shfl_xor(m, d));
            float se = 0.f, ps = 0.f, cnt = 0.f;
            #pragma unroll
            for (int fn = 0; fn < 4; ++fn) {
                float c = (fn == 0) ? c0 : (fn == 1) ? c1 : (fn == 2) ? c2 : c3;
                const int lc = wc + fn * 16 + cl;
                const int gj = colbase + lc;
                const bool self = (gj == gi);
                se += self ? 0.f : __expf(c - m);
                const bool pos = (!self) && (labC[lc] == li);
                ps += pos ? c : 0.f;
                cnt += pos ? 1.f : 0.f;
            }
            #pragma unroll
            for (int d = 1; d < 16; d <<= 1) {
                se  += __shfl_xor(se, d);
                ps  += __shfl_xor(ps, d);
                cnt += __shfl_xor(cnt, d);
            }
            if (cl == 0) partials[(size_t)ct * NROW + gi] = make_float4(m, se, ps, cnt);
        }
    }
}

// ---------------- Kernel D: per-row combine ----------------
__global__ void k_combine(const float4* __restrict__ partials, const float4* __restrict__ ms,
                          float* __restrict__ vals) {
    const int r = blockIdx.x * blockDim.x + threadIdx.x;
    if (r >= NROW) return;
    float M = -3.4e38f;
    #pragma unroll 4
    for (int ct = 0; ct < NCT; ++ct) M = fmaxf(M, partials[(size_t)ct * NROW + r].x);
    float S1 = 0.f, ps = 0.f, cnt = 0.f;
    #pragma unroll 4
    for (int ct = 0; ct < NCT; ++ct) {
        float4 p = partials[(size_t)ct * NROW + r];
        S1 += p.y * __expf(p.x - M);
        ps += p.z;
        cnt += p.w;
    }
    float4 m = ms[r];
    float L = logf(S1 + m.x);
    float val = (ps - cnt * (M + L) + m.y - m.z * L) / (cnt + m.z);
    vals[r] = val;
}

// ---------------- Kernel E: final scalar ----------------
__global__ void k_finalize(const float* __restrict__ vals, float* __restrict__ out) {
    const int t = threadIdx.x;          // 256
    const int lane = t & 63, wid = t >> 6;
    float s = 0.f;
    for (int i = t; i < NROW; i += 256) s += vals[i];
    #pragma unroll
    for (int d = 1; d < 64; d <<= 1) s += __shfl_xor(s, d);
    __shared__ float red[4];
    if (lane == 0) red[wid] = s;
    __syncthreads();
    if (t == 0) out[0] = -(red[0] + red[1] + red[2] + red[3]) * (1.0f / (float)NROW);
}

extern "C" void kernel_launch(void* const* d_in, const int* in_sizes, int n_in,
                              void* d_out, int out_size, void* d_ws, size_t ws_size,
                              hipStream_t stream) {
    const float* q  = (const float*)d_in[0];
    const int* labels = (const int*)d_in[1];
    const float* ml = (const float*)d_in[2];
    const float* mt = (const float*)d_in[3];
    float* out = (float*)d_out;

    char* w = (char*)d_ws;
    u16* qn          = (u16*)w;                      // 8,388,608 B
    float4* partials = (float4*)(w + 8388608);       // 2,097,152 B
    float4* memstats = (float4*)(w + 10485760);      //    65,536 B
    float* vals      = (float*)(w + 10551296);       //    16,384 B

    k_normalize<<<NROW, 256, 0, stream>>>(q, qn);
    k_memstats<<<NROW, 256, 0, stream>>>(ml, mt, memstats);
    k_gemm_stats<<<dim3(NCT, NROW / TILE), 256, 0, stream>>>(qn, labels, partials);
    k_combine<<<NROW / 256, 256, 0, stream>>>(partials, memstats, vals);
    k_finalize<<<1, 256, 0, stream>>>(vals, out);
}